// Round 3
// baseline (29.619 us; speedup 1.0000x reference)
//
#include <hip/hip_runtime.h>
#include <math.h>
#include <stdint.h>

// ---------------------------------------------------------------------------
// VNFrameEstimator, two-kernel structure:
//  K1: coalesced global->LDS staging via global_load_lds(16B) with source-
//      swizzled addresses (h(q)=q^((q>>3)&7) involution) so that per-lane
//      24-float chunk reads (6x ds_read_b128, 96B stride) are bank-conflict-
//      free. Normalize+accumulate in f64 (bit-identical to prior kernel),
//      16-lane shfl reduce, write M (9 doubles, SoA) to workspace.
//  K2: 1 thread/batch 3x3 Jacobi eigensolve in f64 (libm-free), sort, sign-
//      fix, cross, write 3x3 frame.
// ---------------------------------------------------------------------------

#define BPB    16                 // batches per block (16 x 1536B = 24KB LDS)
#define BLOCK  256
#define NSTAGE 6                  // 6 x (4 waves x 1KB) = 24KB

// quad-index involution within each 64-quad row: XOR bits[2:0] with bits[5:3]
__device__ __forceinline__ uint32_t swz(uint32_t q) { return q ^ ((q >> 3) & 7u); }

// 1/sqrt(x), ~6e-14 rel err (f32 seed + 1 f64 NR). x in f32-normal range.
__device__ __forceinline__ double fast_rsqrt1(double x) {
    double r = (double)__builtin_amdgcn_rsqf((float)x);
    double h = -0.5 * x;
    r = r * fma(h, r * r, 1.5);
    return r;
}
// 1/sqrt(x), ~1e-15 rel err (2 NR steps).
__device__ __forceinline__ double fast_rsqrt2(double x) {
    double r = (double)__builtin_amdgcn_rsqf((float)x);
    double h = -0.5 * x;
    r = r * fma(h, r * r, 1.5);
    r = r * fma(h, r * r, 1.5);
    return r;
}
// 1/x, ~1e-15 rel err (2 NR steps). |x| f32-representable (guarded by caller).
__device__ __forceinline__ double fast_rcp(double x) {
    double r = (double)__builtin_amdgcn_rcpf((float)x);
    r = r * fma(-x, r, 2.0);
    r = r * fma(-x, r, 2.0);
    return r;
}

// ------------------------------- Kernel 1 ----------------------------------
__global__ __launch_bounds__(BLOCK) void vn_phase1(
    const float* __restrict__ vf, double* __restrict__ wsd, int B) {
    __shared__ float sbuf[BPB * 384];   // 24 KB, 1536 quads

    const int tid  = threadIdx.x;
    const int wave = tid >> 6;
    const int lane = tid & 63;
    const uint32_t lswz = (uint32_t)lane ^ ((uint32_t)lane >> 3);

    const size_t blockQuadBase = (size_t)blockIdx.x * (BPB * 96); // quads
    const size_t maxQuad = (size_t)B * 96;

    // ---- stage 24KB: physical-linear LDS writes, source-swizzled global ----
#pragma unroll
    for (int t = 0; t < NSTAGE; ++t) {
        const uint32_t rowQuad = (uint32_t)(t * 4 + wave) * 64;
        size_t gq = blockQuadBase + rowQuad + lswz;
        if (gq >= maxQuad) gq = maxQuad - 1;          // safety clamp (pad batches)
        const float* gsrc = vf + gq * 4;
        float* ldst = &sbuf[((size_t)rowQuad + (uint32_t)lane) * 4];
        __builtin_amdgcn_global_load_lds(
            (__attribute__((address_space(1))) void*)(void*)const_cast<float*>(gsrc),
            (__attribute__((address_space(3))) void*)(void*)ldst,
            16, 0, 0);
    }
    __syncthreads();  // compiler drains vmcnt(0) before s_barrier

    // ---- compute: 16 lanes per batch, lane sub owns one 24-float chunk ----
    const int g    = lane >> 4;
    const int sub  = lane & 15;
    const int bslot = wave * 4 + g;                  // 0..15
    const int b = blockIdx.x * BPB + bslot;

    const uint32_t baseQuad = (uint32_t)bslot * 96 + (uint32_t)sub * 6;
    float f[24];
#pragma unroll
    for (int j = 0; j < 6; ++j) {
        const uint32_t pq = swz(baseQuad + (uint32_t)j);
        const float4 q = *reinterpret_cast<const float4*>(&sbuf[pq * 4]);
        f[4 * j + 0] = q.x; f[4 * j + 1] = q.y;
        f[4 * j + 2] = q.z; f[4 * j + 3] = q.w;
    }

    double m[9];
#pragma unroll
    for (int k = 0; k < 9; ++k) m[k] = 0.0;

#pragma unroll
    for (int k = 0; k < 8; ++k) {
        float fx = f[3 * k + 0];
        float fy = f[3 * k + 1];
        float fz = f[3 * k + 2];
        float n2f = fmaf(fx, fx, fmaf(fy, fy, fz * fz));  // f32 norm (matches ref)
        double n2 = (double)n2f;
        double inv = (n2 > 1e-24) ? fast_rsqrt1(n2) : 1e12;
        double x = (double)fx * inv;
        double y = (double)fy * inv;
        double z = (double)fz * inv;
        m[0] = fma(x, x, m[0]);
        m[1] = fma(x, y, m[1]);
        m[2] = fma(x, z, m[2]);
        m[3] = fma(y, y, m[3]);
        m[4] = fma(y, z, m[4]);
        m[5] = fma(z, z, m[5]);
        m[6] += x; m[7] += y; m[8] += z;
    }
#pragma unroll
    for (int off = 1; off < 16; off <<= 1) {
#pragma unroll
        for (int k = 0; k < 9; ++k) m[k] += __shfl_xor(m[k], off);
    }
    if (sub == 0 && b < B) {
#pragma unroll
        for (int k = 0; k < 9; ++k) wsd[(size_t)k * B + b] = m[k];
    }
}

// ------------------------------- Kernel 2 ----------------------------------
template <int P, int Q, int R>
__device__ __forceinline__ void jrot(double (&A)[3][3], double (&V)[3][3]) {
    double apq = A[P][Q];
    if (fabs(apq) > 1e-18) {
        double theta = (A[Q][Q] - A[P][P]) * 0.5 * fast_rcp(apq);
        double q = fma(theta, theta, 1.0);
        double sq = (q < 1e37) ? q * fast_rsqrt2(q) : fabs(theta); // sqrt(q)
        double t = fast_rcp(fabs(theta) + sq);
        if (theta < 0.0) t = -t;
        double c = fast_rsqrt2(fma(t, t, 1.0));
        double s = t * c;
        double apq_t = t * apq;
        A[P][P] = A[P][P] - apq_t;
        A[Q][Q] = A[Q][Q] + apq_t;
        A[P][Q] = 0.0;
        A[Q][P] = 0.0;
        double apr = A[P][R], aqr = A[Q][R];
        A[P][R] = c * apr - s * aqr; A[R][P] = A[P][R];
        A[Q][R] = s * apr + c * aqr; A[R][Q] = A[Q][R];
#pragma unroll
        for (int i = 0; i < 3; ++i) {
            double vip = V[i][P], viq = V[i][Q];
            V[i][P] = c * vip - s * viq;
            V[i][Q] = s * vip + c * viq;
        }
    }
}

__global__ __launch_bounds__(256) void vn_phase2(
    const double* __restrict__ wsd, float* __restrict__ out, int B) {
    const int b = blockIdx.x * 256 + threadIdx.x;
    if (b >= B) return;

    double m[9];
#pragma unroll
    for (int k = 0; k < 9; ++k) m[k] = wsd[(size_t)k * B + b];

    double A[3][3], V[3][3];
    A[0][0] = m[0] + (double)1e-05f;
    A[0][1] = m[1]; A[1][0] = m[1];
    A[0][2] = m[2]; A[2][0] = m[2];
    A[1][1] = m[3] + (double)2e-05f;
    A[1][2] = m[4]; A[2][1] = m[4];
    A[2][2] = m[5] + (double)3e-05f;
#pragma unroll
    for (int i = 0; i < 3; ++i)
#pragma unroll
        for (int j = 0; j < 3; ++j) V[i][j] = (i == j) ? 1.0 : 0.0;

#pragma unroll
    for (int sweep = 0; sweep < 6; ++sweep) {
        jrot<0, 1, 2>(A, V);
        jrot<0, 2, 1>(A, V);
        jrot<1, 2, 0>(A, V);
    }

    double e0 = A[0][0], e1 = A[1][1], e2 = A[2][2];
    double c0x = V[0][0], c0y = V[1][0], c0z = V[2][0];
    double c1x = V[0][1], c1y = V[1][1], c1z = V[2][1];
    double c2x = V[0][2], c2y = V[1][2], c2z = V[2][2];

#define CSWAP(ea, eb, ax, ay, az, bx, by, bz)                         \
    if (ea > eb) {                                                    \
        double t_;                                                    \
        t_ = ea; ea = eb; eb = t_;                                    \
        t_ = ax; ax = bx; bx = t_;                                    \
        t_ = ay; ay = by; by = t_;                                    \
        t_ = az; az = bz; bz = t_;                                    \
    }
    CSWAP(e0, e1, c0x, c0y, c0z, c1x, c1y, c1z)
    CSWAP(e1, e2, c1x, c1y, c1z, c2x, c2y, c2z)
    CSWAP(e0, e1, c0x, c0y, c0z, c1x, c1y, c1z)
#undef CSWAP

    double s0 = m[6], s1 = m[7], s2 = m[8];
    double d1 = s0 * c0x + s1 * c0y + s2 * c0z;
    double f1 = (d1 < 0.0) ? -1.0 : 1.0;
    c0x *= f1; c0y *= f1; c0z *= f1;
    double d2 = s0 * c1x + s1 * c1y + s2 * c1z;
    double f2 = (d2 < 0.0) ? -1.0 : 1.0;
    c1x *= f2; c1y *= f2; c1z *= f2;

    double v3x = c0y * c1z - c0z * c1y;
    double v3y = c0z * c1x - c0x * c1z;
    double v3z = c0x * c1y - c0y * c1x;

    float* o = out + (size_t)b * 9;
    o[0] = (float)c0x; o[1] = (float)c1x; o[2] = (float)v3x;
    o[3] = (float)c0y; o[4] = (float)c1y; o[5] = (float)v3y;
    o[6] = (float)c0z; o[7] = (float)c1z; o[8] = (float)v3z;
}

extern "C" void kernel_launch(void* const* d_in, const int* in_sizes, int n_in,
                              void* d_out, int out_size, void* d_ws, size_t ws_size,
                              hipStream_t stream) {
    const float* vf = (const float*)d_in[0];
    float* out = (float*)d_out;
    double* wsd = (double*)d_ws;   // 9 * B doubles (SoA), ~4.7 MB
    const int B = in_sizes[0] / 384;
    const int grid1 = (B + BPB - 1) / BPB;
    vn_phase1<<<dim3(grid1), dim3(BLOCK), 0, stream>>>(vf, wsd, B);
    const int grid2 = (B + 255) / 256;
    vn_phase2<<<dim3(grid2), dim3(256), 0, stream>>>(wsd, out, B);
}